// Round 5
// baseline (148.175 us; speedup 1.0000x reference)
//
#include <hip/hip_runtime.h>
#include <math.h>

// Dims fixed by reference setup_inputs
#define B_ 4
#define S_ 2048
#define D_ 1024
#define G_ 512
#define T_ 2047          // diff rows per batch
#define R_ 8188          // B_*T_ valid rows
#define RPAD 8192
#define MT 32            // diff rows per fused block
#define ABST 520         // AB LDS row stride (elems): 1040 B, 16-B aligned

typedef __attribute__((ext_vector_type(8))) short short8;
typedef __attribute__((ext_vector_type(4))) short s16x4;
typedef __attribute__((ext_vector_type(4))) float f32x4;

// ws byte offsets
#define WSOFF_RG2  0u           // 512 f
#define WSOFF_MAGW 2048u        // 8192 f
#define WSOFF_BP1  34816u       // Bpack1 [128][512] short8 (1 MB)
#define WSOFF_BP2  1083392u     // Bpack2 [64][1024] short8 (1 MB)
#define WSOFF_NH   2131968u     // normh [8192][1024] bf16 (16 MB)
#define WSOFF_IH   18909184u    // inflh [8192][1024] bf16 (16 MB)

__device__ inline short to_bf16(float f) {
    union { float f; unsigned u; } v; v.f = f;
    unsigned r = v.u + 0x7fffu + ((v.u >> 16) & 1u);
    return (short)(r >> 16);
}
__device__ inline float fb(unsigned short h) {
    union { unsigned u; float f; } v;
    v.u = ((unsigned)h) << 16;
    return v.f;
}

// ---------------------------------------------------------------------------
// prep: blocks 0..127  -> rg2 + Bpack1 (4 g-rows per block, one wave each)
//       blocks 128..383 -> Bpack2 (gg = (blk-128)>>2, d-chunk = (blk-128)&3)
// ---------------------------------------------------------------------------
__global__ __launch_bounds__(256) void prep_kernel(const float* __restrict__ guid,
                                                   float* __restrict__ rg2,
                                                   short8* __restrict__ Bp1,
                                                   short8* __restrict__ Bp2) {
    int blk = blockIdx.x, tid = threadIdx.x;
    if (blk < 128) {
        int g = blk * 4 + (tid >> 6);
        int lane = tid & 63;
        const float4* gp = (const float4*)(guid + (size_t)g * D_);
        float ss = 0.f;
#pragma unroll
        for (int i = 0; i < 4; ++i) {
            float4 v = gp[lane + 64 * i];
            ss += v.x * v.x + v.y * v.y + v.z * v.z + v.w * v.w;
        }
#pragma unroll
        for (int m = 32; m >= 1; m >>= 1) ss += __shfl_xor(ss, m, 64);
        if (lane == 0) rg2[g] = 2.0f / fmaxf(sqrtf(ss), 1e-8f);
#pragma unroll
        for (int h = 0; h < 2; ++h) {
            int kg = lane + 64 * h;
            const float* src = guid + (size_t)g * D_ + kg * 8;
            short8 v;
#pragma unroll
            for (int j = 0; j < 8; ++j) v[j] = to_bf16(src[j]);
            Bp1[(size_t)kg * G_ + g] = v;
        }
    } else {
        int idx = blk - 128;
        int gg = idx >> 2;
        int d = (idx & 3) * 256 + tid;
        short8 v;
#pragma unroll
        for (int j = 0; j < 8; ++j) v[j] = to_bf16(guid[(size_t)(gg * 8 + j) * D_ + d]);
        Bp2[(size_t)gg * D_ + d] = v;
    }
}

// ---------------------------------------------------------------------------
// fused: 32-row tile, 16 waves. diff/norm -> gemm1 (2 k-passes, depth-2 B
// prefetch) -> softmax -> gemm2 (2 d-passes, depth-2) -> normh/inflh bf16.
// ---------------------------------------------------------------------------
__global__ __launch_bounds__(1024, 4) void fused_kernel(const float* __restrict__ emb,
                                                        const short8* __restrict__ Bp1,
                                                        const short8* __restrict__ Bp2,
                                                        const float* __restrict__ rg2,
                                                        float* __restrict__ magw,
                                                        short* __restrict__ normh,
                                                        short* __restrict__ inflh) {
    __shared__ short AB[MT][ABST];      // normed halves, then softmax weights
    __shared__ float rg2s[G_];
    __shared__ float pred[MT][16];
    __shared__ float redmx[MT], redrs[MT];

    const int tid = threadIdx.x;
    const int wave = tid >> 6, lane = tid & 63;
    const int l15 = lane & 15, quad = lane >> 4;
    const int r0 = blockIdx.x * MT;

    if (tid < G_) rg2s[tid] = rg2[tid];

    // ---- Phase 1: diff + normalize, 2 rows/wave; k<512 half -> LDS,
    //      k>=512 half held in regs; normh bf16 -> global ----
    s16x4 hold[2][2];
#pragma unroll
    for (int i = 0; i < 2; ++i) {
        int rr = wave * 2 + i;
        int R = r0 + rr;
        if (R < R_) {
            int b = R / T_;
            int t = R - b * T_;
            const float4* p = (const float4*)(emb + ((size_t)b * S_ + t) * D_);
            float4 dv[4]; float ss = 0.f;
#pragma unroll
            for (int j = 0; j < 4; ++j) {
                float4 x0 = p[lane + 64 * j];
                float4 x1 = p[lane + 64 * j + 256];
                dv[j] = make_float4(x1.x - x0.x, x1.y - x0.y, x1.z - x0.z, x1.w - x0.w);
                ss += dv[j].x * dv[j].x + dv[j].y * dv[j].y + dv[j].z * dv[j].z + dv[j].w * dv[j].w;
            }
#pragma unroll
            for (int m = 32; m >= 1; m >>= 1) ss += __shfl_xor(ss, m, 64);
            float mag = sqrtf(ss);
            float rmag = (mag > 1e-6f) ? (1.0f / mag) : 0.0f;
            if (lane == 0) magw[R] = tanhf(2.0f * mag);
            s16x4 h[4];
#pragma unroll
            for (int j = 0; j < 4; ++j) {
                h[j][0] = to_bf16(dv[j].x * rmag); h[j][1] = to_bf16(dv[j].y * rmag);
                h[j][2] = to_bf16(dv[j].z * rmag); h[j][3] = to_bf16(dv[j].w * rmag);
            }
            short* nb = normh + (size_t)R * D_ + 4 * lane;
#pragma unroll
            for (int j = 0; j < 4; ++j) *(s16x4*)(nb + 256 * j) = h[j];
            *(s16x4*)&AB[rr][4 * lane] = h[0];
            *(s16x4*)&AB[rr][4 * lane + 256] = h[1];
            hold[i][0] = h[2]; hold[i][1] = h[3];
        } else {
            s16x4 z = (s16x4)0;
            *(s16x4*)&AB[rr][4 * lane] = z;
            *(s16x4*)&AB[rr][4 * lane + 256] = z;
            hold[i][0] = z; hold[i][1] = z;
        }
    }
    __syncthreads();

    // ---- Phase 2: gemm1, wave owns g in [32w, 32w+32); depth-2 prefetch ----
    f32x4 acc1[2][2];
#pragma unroll
    for (int mt = 0; mt < 2; ++mt)
#pragma unroll
        for (int nt = 0; nt < 2; ++nt) acc1[mt][nt] = (f32x4)0.f;
#pragma unroll
    for (int p = 0; p < 2; ++p) {
        if (p == 1) {
            __syncthreads();
#pragma unroll
            for (int i = 0; i < 2; ++i) {
                int rr = wave * 2 + i;
                *(s16x4*)&AB[rr][4 * lane] = hold[i][0];
                *(s16x4*)&AB[rr][4 * lane + 256] = hold[i][1];
            }
            __syncthreads();
        }
        const short8* Bb = Bp1 + ((size_t)(64 * p + quad)) * G_ + wave * 32 + l15;
        short8 buf[2][2];
        buf[0][0] = Bb[0];             buf[0][1] = Bb[16];
        buf[1][0] = Bb[4 * G_];        buf[1][1] = Bb[4 * G_ + 16];
#pragma unroll
        for (int ks = 0; ks < 16; ++ks) {
            short8 b0 = buf[ks & 1][0], b1 = buf[ks & 1][1];
            if (ks < 14) {
                const short8* Bx = Bb + (size_t)(ks + 2) * 4 * G_;
                buf[ks & 1][0] = Bx[0]; buf[ks & 1][1] = Bx[16];
            }
            short8 a0 = *(const short8*)&AB[l15][ks * 32 + quad * 8];
            short8 a1 = *(const short8*)&AB[16 + l15][ks * 32 + quad * 8];
            acc1[0][0] = __builtin_amdgcn_mfma_f32_16x16x32_bf16(a0, b0, acc1[0][0], 0, 0, 0);
            acc1[0][1] = __builtin_amdgcn_mfma_f32_16x16x32_bf16(a0, b1, acc1[0][1], 0, 0, 0);
            acc1[1][0] = __builtin_amdgcn_mfma_f32_16x16x32_bf16(a1, b0, acc1[1][0], 0, 0, 0);
            acc1[1][1] = __builtin_amdgcn_mfma_f32_16x16x32_bf16(a1, b1, acc1[1][1], 0, 0, 0);
        }
    }

    // ---- Phase 3: cross-wave softmax; weights -> AB (gemm2 A-frags) ----
    {
        float pmax[2][4];
#pragma unroll
        for (int mt = 0; mt < 2; ++mt)
#pragma unroll
            for (int r2 = 0; r2 < 4; ++r2) pmax[mt][r2] = -1e30f;
#pragma unroll
        for (int mt = 0; mt < 2; ++mt)
#pragma unroll
            for (int nt = 0; nt < 2; ++nt) {
                float rgv = rg2s[wave * 32 + nt * 16 + l15];
#pragma unroll
                for (int r2 = 0; r2 < 4; ++r2) {
                    float lg = acc1[mt][nt][r2] * rgv;
                    acc1[mt][nt][r2] = lg;
                    pmax[mt][r2] = fmaxf(pmax[mt][r2], lg);
                }
            }
#pragma unroll
        for (int m = 8; m >= 1; m >>= 1)
#pragma unroll
            for (int mt = 0; mt < 2; ++mt)
#pragma unroll
                for (int r2 = 0; r2 < 4; ++r2)
                    pmax[mt][r2] = fmaxf(pmax[mt][r2], __shfl_xor(pmax[mt][r2], m, 16));
        if (l15 == 0) {
#pragma unroll
            for (int mt = 0; mt < 2; ++mt)
#pragma unroll
                for (int r2 = 0; r2 < 4; ++r2)
                    pred[mt * 16 + quad * 4 + r2][wave] = pmax[mt][r2];
        }
        __syncthreads();
        if (tid < MT) {
            float m = pred[tid][0];
#pragma unroll
            for (int w2 = 1; w2 < 16; ++w2) m = fmaxf(m, pred[tid][w2]);
            redmx[tid] = m;
        }
        __syncthreads();
        float psum[2][4];
#pragma unroll
        for (int mt = 0; mt < 2; ++mt)
#pragma unroll
            for (int r2 = 0; r2 < 4; ++r2) psum[mt][r2] = 0.f;
#pragma unroll
        for (int mt = 0; mt < 2; ++mt)
#pragma unroll
            for (int nt = 0; nt < 2; ++nt)
#pragma unroll
                for (int r2 = 0; r2 < 4; ++r2) {
                    float e = __expf(acc1[mt][nt][r2] - redmx[mt * 16 + quad * 4 + r2]);
                    acc1[mt][nt][r2] = e;
                    psum[mt][r2] += e;
                }
#pragma unroll
        for (int m = 8; m >= 1; m >>= 1)
#pragma unroll
            for (int mt = 0; mt < 2; ++mt)
#pragma unroll
                for (int r2 = 0; r2 < 4; ++r2)
                    psum[mt][r2] += __shfl_xor(psum[mt][r2], m, 16);
        if (l15 == 0) {
#pragma unroll
            for (int mt = 0; mt < 2; ++mt)
#pragma unroll
                for (int r2 = 0; r2 < 4; ++r2)
                    pred[mt * 16 + quad * 4 + r2][wave] = psum[mt][r2];
        }
        __syncthreads();
        if (tid < MT) {
            float s = 0.f;
#pragma unroll
            for (int w2 = 0; w2 < 16; ++w2) s += pred[tid][w2];
            redrs[tid] = 1.0f / s;
        }
        __syncthreads();
#pragma unroll
        for (int mt = 0; mt < 2; ++mt)
#pragma unroll
            for (int nt = 0; nt < 2; ++nt)
#pragma unroll
                for (int r2 = 0; r2 < 4; ++r2) {
                    int row = mt * 16 + quad * 4 + r2;
                    AB[row][wave * 32 + nt * 16 + l15] =
                        to_bf16(acc1[mt][nt][r2] * redrs[row]);
                }
    }
    __syncthreads();

    // ---- Phase 4/5: gemm2 in two 32-d passes; depth-2 prefetch; inflh out ----
#pragma unroll
    for (int dp = 0; dp < 2; ++dp) {
        int d0 = wave * 64 + dp * 32;
        f32x4 acc2[2][2];
#pragma unroll
        for (int mt = 0; mt < 2; ++mt)
#pragma unroll
            for (int nt = 0; nt < 2; ++nt) acc2[mt][nt] = (f32x4)0.f;
        const short8* Bb = Bp2 + (size_t)quad * D_ + d0 + l15;
        short8 buf[2][2];
        buf[0][0] = Bb[0];            buf[0][1] = Bb[16];
        buf[1][0] = Bb[4 * D_];       buf[1][1] = Bb[4 * D_ + 16];
#pragma unroll
        for (int ks = 0; ks < 16; ++ks) {
            short8 b0 = buf[ks & 1][0], b1 = buf[ks & 1][1];
            if (ks < 14) {
                const short8* Bx = Bb + (size_t)(ks + 2) * 4 * D_;
                buf[ks & 1][0] = Bx[0]; buf[ks & 1][1] = Bx[16];
            }
            short8 a0 = *(const short8*)&AB[l15][ks * 32 + quad * 8];
            short8 a1 = *(const short8*)&AB[16 + l15][ks * 32 + quad * 8];
            acc2[0][0] = __builtin_amdgcn_mfma_f32_16x16x32_bf16(a0, b0, acc2[0][0], 0, 0, 0);
            acc2[0][1] = __builtin_amdgcn_mfma_f32_16x16x32_bf16(a0, b1, acc2[0][1], 0, 0, 0);
            acc2[1][0] = __builtin_amdgcn_mfma_f32_16x16x32_bf16(a1, b0, acc2[1][0], 0, 0, 0);
            acc2[1][1] = __builtin_amdgcn_mfma_f32_16x16x32_bf16(a1, b1, acc2[1][1], 0, 0, 0);
        }
#pragma unroll
        for (int mt = 0; mt < 2; ++mt)
#pragma unroll
            for (int nt = 0; nt < 2; ++nt) {
                int d = d0 + nt * 16 + l15;
#pragma unroll
                for (int r2 = 0; r2 < 4; ++r2) {
                    int R = r0 + mt * 16 + quad * 4 + r2;
                    if (R < R_) inflh[(size_t)R * D_ + d] = to_bf16(acc2[mt][nt][r2]);
                }
            }
    }
}

// ---------------------------------------------------------------------------
// combine: one block per (b,s); all 8 taps loaded independently (no serial
// ring). XCD-slab swizzle for L2 reuse of rows across neighboring s.
// ---------------------------------------------------------------------------
__global__ __launch_bounds__(256) void combine_kernel(const float* __restrict__ magw,
                                                      const unsigned short* __restrict__ normh,
                                                      const unsigned short* __restrict__ inflh,
                                                      float* __restrict__ out) {
    int flat = blockIdx.x;
    int virt = ((flat & 7) << 10) | (flat >> 3);   // same XCD -> contiguous s-slab
    int b = virt >> 11;
    int s = virt & (S_ - 1);
    int tid = threadIdx.x;
    size_t rbase = (size_t)b * T_;

    int w = (s < 8) ? s : 8;
    float rw = (w > 1) ? 0.9f / (float)(w - 1) : 0.0f;
    float wt[8];
    float wsum = 0.f;
#pragma unroll
    for (int j = 0; j < 8; ++j) {
        float v = 0.f;
        if (j < w) v = (0.1f + rw * (float)j) * magw[rbase + s - w + j];
        wt[j] = v;
        wsum += v;
    }
    float rws = 1.0f / fmaxf(wsum, 1e-8f);

    float4 acc = make_float4(0.f, 0.f, 0.f, 0.f);
#pragma unroll
    for (int j = 0; j < 8; ++j) {
        if (j < w) {
            size_t off = (rbase + (size_t)(s - w + j)) * D_ + tid * 4;
            ushort4 n = *(const ushort4*)(normh + off);
            ushort4 iv = *(const ushort4*)(inflh + off);
            float c = wt[j];
            acc.x += c * (0.6f * fb(n.x) + 0.4f * fb(iv.x));
            acc.y += c * (0.6f * fb(n.y) + 0.4f * fb(iv.y));
            acc.z += c * (0.6f * fb(n.z) + 0.4f * fb(iv.z));
            acc.w += c * (0.6f * fb(n.w) + 0.4f * fb(iv.w));
        }
    }
    *(float4*)&out[((size_t)b * S_ + s) * D_ + tid * 4] =
        make_float4(acc.x * rws, acc.y * rws, acc.z * rws, acc.w * rws);
}

// ---------------------------------------------------------------------------
extern "C" void kernel_launch(void* const* d_in, const int* in_sizes, int n_in,
                              void* d_out, int out_size, void* d_ws, size_t ws_size,
                              hipStream_t stream) {
    const float* emb  = (const float*)d_in[0];
    const float* guid = (const float*)d_in[1];
    float* out = (float*)d_out;
    char* ws = (char*)d_ws;

    float*  rg2   = (float*)(ws + WSOFF_RG2);
    float*  magw  = (float*)(ws + WSOFF_MAGW);
    short8* Bp1   = (short8*)(ws + WSOFF_BP1);
    short8* Bp2   = (short8*)(ws + WSOFF_BP2);
    short*  normh = (short*)(ws + WSOFF_NH);
    short*  inflh = (short*)(ws + WSOFF_IH);

    prep_kernel<<<384, 256, 0, stream>>>(guid, rg2, Bp1, Bp2);
    fused_kernel<<<RPAD / MT, 1024, 0, stream>>>(emb, Bp1, Bp2, rg2, magw, normh, inflh);
    combine_kernel<<<B_ * S_, 256, 0, stream>>>(magw, (const unsigned short*)normh,
                                                (const unsigned short*)inflh, out);
}

// Round 6
// 145.264 us; speedup vs baseline: 1.0200x; 1.0200x over previous
//
#include <hip/hip_runtime.h>
#include <math.h>

// Dims fixed by reference setup_inputs
#define B_ 4
#define S_ 2048
#define D_ 1024
#define G_ 512
#define T_ 2047          // diff rows per batch
#define R_ 8188          // B_*T_ valid rows
#define RPAD 8192
#define MT 32            // diff rows per fused block
#define ABST 520         // AB LDS row stride (elems): 1040 B, 16-B aligned

typedef __attribute__((ext_vector_type(8))) short short8;
typedef __attribute__((ext_vector_type(4))) short s16x4;
typedef __attribute__((ext_vector_type(4))) float f32x4;

// ws byte offsets
#define WSOFF_RG2  0u           // 512 f
#define WSOFF_MAGW 2048u        // 8192 f
#define WSOFF_BP1  34816u       // Bpack1 [128][512] short8 (1 MB)
#define WSOFF_BP2  1083392u     // Bpack2 [64][1024] short8 (1 MB)
#define WSOFF_NH   2131968u     // normh [8192][1024] bf16 (16 MB)
#define WSOFF_IH   18909184u    // inflh [8192][1024] bf16 (16 MB)

__device__ inline short to_bf16(float f) {
    union { float f; unsigned u; } v; v.f = f;
    unsigned r = v.u + 0x7fffu + ((v.u >> 16) & 1u);
    return (short)(r >> 16);
}
__device__ inline float fb(unsigned short h) {
    union { unsigned u; float f; } v;
    v.u = ((unsigned)h) << 16;
    return v.f;
}

// ---------------------------------------------------------------------------
// prep: blocks 0..127  -> rg2 + Bpack1 (4 g-rows per block, one wave each)
//       blocks 128..383 -> Bpack2
// ---------------------------------------------------------------------------
__global__ __launch_bounds__(256) void prep_kernel(const float* __restrict__ guid,
                                                   float* __restrict__ rg2,
                                                   short8* __restrict__ Bp1,
                                                   short8* __restrict__ Bp2) {
    int blk = blockIdx.x, tid = threadIdx.x;
    if (blk < 128) {
        int g = blk * 4 + (tid >> 6);
        int lane = tid & 63;
        const float4* gp = (const float4*)(guid + (size_t)g * D_);
        float ss = 0.f;
#pragma unroll
        for (int i = 0; i < 4; ++i) {
            float4 v = gp[lane + 64 * i];
            ss += v.x * v.x + v.y * v.y + v.z * v.z + v.w * v.w;
        }
#pragma unroll
        for (int m = 32; m >= 1; m >>= 1) ss += __shfl_xor(ss, m, 64);
        if (lane == 0) rg2[g] = 2.0f / fmaxf(sqrtf(ss), 1e-8f);
#pragma unroll
        for (int h = 0; h < 2; ++h) {
            int kg = lane + 64 * h;
            const float* src = guid + (size_t)g * D_ + kg * 8;
            short8 v;
#pragma unroll
            for (int j = 0; j < 8; ++j) v[j] = to_bf16(src[j]);
            Bp1[(size_t)kg * G_ + g] = v;
        }
    } else {
        int idx = blk - 128;
        int gg = idx >> 2;
        int d = (idx & 3) * 256 + tid;
        short8 v;
#pragma unroll
        for (int j = 0; j < 8; ++j) v[j] = to_bf16(guid[(size_t)(gg * 8 + j) * D_ + d]);
        Bp2[(size_t)gg * D_ + d] = v;
    }
}

// ---------------------------------------------------------------------------
// fused (R4 version): 32-row tile, 16 waves. diff/norm -> gemm1 (2 k-passes,
// depth-1 prefetch) -> softmax -> gemm2 (single pass) -> normh/inflh bf16.
// ---------------------------------------------------------------------------
__global__ __launch_bounds__(1024, 4) void fused_kernel(const float* __restrict__ emb,
                                                        const short8* __restrict__ Bp1,
                                                        const short8* __restrict__ Bp2,
                                                        const float* __restrict__ rg2,
                                                        float* __restrict__ magw,
                                                        short* __restrict__ normh,
                                                        short* __restrict__ inflh) {
    __shared__ short AB[MT][ABST];      // normed halves, then softmax weights
    __shared__ float rg2s[G_];
    __shared__ float pred[MT][16];
    __shared__ float redmx[MT], redrs[MT];

    const int tid = threadIdx.x;
    const int wave = tid >> 6, lane = tid & 63;
    const int l15 = lane & 15, quad = lane >> 4;
    const int r0 = blockIdx.x * MT;

    if (tid < G_) rg2s[tid] = rg2[tid];

    // ---- Phase 1: diff + normalize ----
    s16x4 hold[2][2];
#pragma unroll
    for (int i = 0; i < 2; ++i) {
        int rr = wave * 2 + i;
        int R = r0 + rr;
        if (R < R_) {
            int b = R / T_;
            int t = R - b * T_;
            const float4* p = (const float4*)(emb + ((size_t)b * S_ + t) * D_);
            float4 dv[4]; float ss = 0.f;
#pragma unroll
            for (int j = 0; j < 4; ++j) {
                float4 x0 = p[lane + 64 * j];
                float4 x1 = p[lane + 64 * j + 256];
                dv[j] = make_float4(x1.x - x0.x, x1.y - x0.y, x1.z - x0.z, x1.w - x0.w);
                ss += dv[j].x * dv[j].x + dv[j].y * dv[j].y + dv[j].z * dv[j].z + dv[j].w * dv[j].w;
            }
#pragma unroll
            for (int m = 32; m >= 1; m >>= 1) ss += __shfl_xor(ss, m, 64);
            float mag = sqrtf(ss);
            float rmag = (mag > 1e-6f) ? (1.0f / mag) : 0.0f;
            if (lane == 0) magw[R] = tanhf(2.0f * mag);
            s16x4 h[4];
#pragma unroll
            for (int j = 0; j < 4; ++j) {
                h[j][0] = to_bf16(dv[j].x * rmag); h[j][1] = to_bf16(dv[j].y * rmag);
                h[j][2] = to_bf16(dv[j].z * rmag); h[j][3] = to_bf16(dv[j].w * rmag);
            }
            short* nb = normh + (size_t)R * D_ + 4 * lane;
#pragma unroll
            for (int j = 0; j < 4; ++j) *(s16x4*)(nb + 256 * j) = h[j];
            *(s16x4*)&AB[rr][4 * lane] = h[0];
            *(s16x4*)&AB[rr][4 * lane + 256] = h[1];
            hold[i][0] = h[2]; hold[i][1] = h[3];
        } else {
            s16x4 z = (s16x4)0;
            *(s16x4*)&AB[rr][4 * lane] = z;
            *(s16x4*)&AB[rr][4 * lane + 256] = z;
            hold[i][0] = z; hold[i][1] = z;
        }
    }
    __syncthreads();

    // ---- Phase 2: gemm1, wave owns g in [32w, 32w+32) ----
    f32x4 acc1[2][2];
#pragma unroll
    for (int mt = 0; mt < 2; ++mt)
#pragma unroll
        for (int nt = 0; nt < 2; ++nt) acc1[mt][nt] = (f32x4)0.f;
#pragma unroll
    for (int p = 0; p < 2; ++p) {
        if (p == 1) {
            __syncthreads();
#pragma unroll
            for (int i = 0; i < 2; ++i) {
                int rr = wave * 2 + i;
                *(s16x4*)&AB[rr][4 * lane] = hold[i][0];
                *(s16x4*)&AB[rr][4 * lane + 256] = hold[i][1];
            }
            __syncthreads();
        }
        const short8* Bb = Bp1 + ((size_t)(64 * p + quad)) * G_ + wave * 32 + l15;
        short8 bc0 = Bb[0], bc1 = Bb[16], bn0, bn1;
        for (int ks = 0; ks < 16; ++ks) {
            if (ks < 15) {
                const short8* Bx = Bb + (size_t)(ks + 1) * 4 * G_;
                bn0 = Bx[0]; bn1 = Bx[16];
            }
            short8 a0 = *(const short8*)&AB[l15][ks * 32 + quad * 8];
            short8 a1 = *(const short8*)&AB[16 + l15][ks * 32 + quad * 8];
            acc1[0][0] = __builtin_amdgcn_mfma_f32_16x16x32_bf16(a0, bc0, acc1[0][0], 0, 0, 0);
            acc1[0][1] = __builtin_amdgcn_mfma_f32_16x16x32_bf16(a0, bc1, acc1[0][1], 0, 0, 0);
            acc1[1][0] = __builtin_amdgcn_mfma_f32_16x16x32_bf16(a1, bc0, acc1[1][0], 0, 0, 0);
            acc1[1][1] = __builtin_amdgcn_mfma_f32_16x16x32_bf16(a1, bc1, acc1[1][1], 0, 0, 0);
            bc0 = bn0; bc1 = bn1;
        }
    }

    // ---- Phase 3: cross-wave softmax; weights -> AB ----
    {
        float pmax[2][4];
#pragma unroll
        for (int mt = 0; mt < 2; ++mt)
#pragma unroll
            for (int r2 = 0; r2 < 4; ++r2) pmax[mt][r2] = -1e30f;
#pragma unroll
        for (int mt = 0; mt < 2; ++mt)
#pragma unroll
            for (int nt = 0; nt < 2; ++nt) {
                float rgv = rg2s[wave * 32 + nt * 16 + l15];
#pragma unroll
                for (int r2 = 0; r2 < 4; ++r2) {
                    float lg = acc1[mt][nt][r2] * rgv;
                    acc1[mt][nt][r2] = lg;
                    pmax[mt][r2] = fmaxf(pmax[mt][r2], lg);
                }
            }
#pragma unroll
        for (int m = 8; m >= 1; m >>= 1)
#pragma unroll
            for (int mt = 0; mt < 2; ++mt)
#pragma unroll
                for (int r2 = 0; r2 < 4; ++r2)
                    pmax[mt][r2] = fmaxf(pmax[mt][r2], __shfl_xor(pmax[mt][r2], m, 16));
        if (l15 == 0) {
#pragma unroll
            for (int mt = 0; mt < 2; ++mt)
#pragma unroll
                for (int r2 = 0; r2 < 4; ++r2)
                    pred[mt * 16 + quad * 4 + r2][wave] = pmax[mt][r2];
        }
        __syncthreads();
        if (tid < MT) {
            float m = pred[tid][0];
#pragma unroll
            for (int w2 = 1; w2 < 16; ++w2) m = fmaxf(m, pred[tid][w2]);
            redmx[tid] = m;
        }
        __syncthreads();
        float psum[2][4];
#pragma unroll
        for (int mt = 0; mt < 2; ++mt)
#pragma unroll
            for (int r2 = 0; r2 < 4; ++r2) psum[mt][r2] = 0.f;
#pragma unroll
        for (int mt = 0; mt < 2; ++mt)
#pragma unroll
            for (int nt = 0; nt < 2; ++nt)
#pragma unroll
                for (int r2 = 0; r2 < 4; ++r2) {
                    float e = __expf(acc1[mt][nt][r2] - redmx[mt * 16 + quad * 4 + r2]);
                    acc1[mt][nt][r2] = e;
                    psum[mt][r2] += e;
                }
#pragma unroll
        for (int m = 8; m >= 1; m >>= 1)
#pragma unroll
            for (int mt = 0; mt < 2; ++mt)
#pragma unroll
                for (int r2 = 0; r2 < 4; ++r2)
                    psum[mt][r2] += __shfl_xor(psum[mt][r2], m, 16);
        if (l15 == 0) {
#pragma unroll
            for (int mt = 0; mt < 2; ++mt)
#pragma unroll
                for (int r2 = 0; r2 < 4; ++r2)
                    pred[mt * 16 + quad * 4 + r2][wave] = psum[mt][r2];
        }
        __syncthreads();
        if (tid < MT) {
            float s = 0.f;
#pragma unroll
            for (int w2 = 0; w2 < 16; ++w2) s += pred[tid][w2];
            redrs[tid] = 1.0f / s;
        }
        __syncthreads();
#pragma unroll
        for (int mt = 0; mt < 2; ++mt)
#pragma unroll
            for (int nt = 0; nt < 2; ++nt)
#pragma unroll
                for (int r2 = 0; r2 < 4; ++r2) {
                    int row = mt * 16 + quad * 4 + r2;
                    AB[row][wave * 32 + nt * 16 + l15] =
                        to_bf16(acc1[mt][nt][r2] * redrs[row]);
                }
    }
    __syncthreads();

    // ---- Phase 4: gemm2 single pass, wave owns d in [64w, 64w+64) ----
    f32x4 acc2[2][4];
#pragma unroll
    for (int mt = 0; mt < 2; ++mt)
#pragma unroll
        for (int nt = 0; nt < 4; ++nt) acc2[mt][nt] = (f32x4)0.f;
    {
        const short8* Bb = Bp2 + (size_t)quad * D_ + wave * 64 + l15;
        short8 bc[4], bn[4];
#pragma unroll
        for (int nt = 0; nt < 4; ++nt) bc[nt] = Bb[nt * 16];
        for (int ks = 0; ks < 16; ++ks) {
            if (ks < 15) {
                const short8* Bx = Bb + (size_t)(ks + 1) * 4 * D_;
#pragma unroll
                for (int nt = 0; nt < 4; ++nt) bn[nt] = Bx[nt * 16];
            }
            short8 a0 = *(const short8*)&AB[l15][ks * 32 + quad * 8];
            short8 a1 = *(const short8*)&AB[16 + l15][ks * 32 + quad * 8];
#pragma unroll
            for (int nt = 0; nt < 4; ++nt) {
                acc2[0][nt] = __builtin_amdgcn_mfma_f32_16x16x32_bf16(a0, bc[nt], acc2[0][nt], 0, 0, 0);
                acc2[1][nt] = __builtin_amdgcn_mfma_f32_16x16x32_bf16(a1, bc[nt], acc2[1][nt], 0, 0, 0);
            }
#pragma unroll
            for (int nt = 0; nt < 4; ++nt) bc[nt] = bn[nt];
        }
    }

    // ---- Phase 5: influence bf16 out (contiguous 128 B per row per wave) ----
#pragma unroll
    for (int mt = 0; mt < 2; ++mt)
#pragma unroll
        for (int nt = 0; nt < 4; ++nt) {
            int d = wave * 64 + nt * 16 + l15;
#pragma unroll
            for (int r2 = 0; r2 < 4; ++r2) {
                int R = r0 + mt * 16 + quad * 4 + r2;
                if (R < R_) inflh[(size_t)R * D_ + d] = to_bf16(acc2[mt][nt][r2]);
            }
        }
}

// ---------------------------------------------------------------------------
// combine: block-level 1-D convolution. Block = 16 outputs x 512-dim half.
// Interior: load 23 rows ONCE each (independent loads), scatter into 16
// accumulators with compile-time tap weights (w=8 uniform for s>=8).
// grid = B_ * 128 * 2 = 1024.
// ---------------------------------------------------------------------------
__global__ __launch_bounds__(256) void combine_kernel(const float* __restrict__ magw,
                                                      const unsigned short* __restrict__ normh,
                                                      const unsigned short* __restrict__ inflh,
                                                      float* __restrict__ out) {
    int blk = blockIdx.x;
    int half = blk & 1;
    int rest = blk >> 1;
    int b = rest >> 7;
    int s0 = (rest & 127) * 16;
    int tid = threadIdx.x;
    int d = half * 512 + tid * 2;
    size_t rbase = (size_t)b * T_;
    const float C = 0.9f / 7.0f;

    if (s0 != 0) {
        float2 acc[16]; float ws[16];
#pragma unroll
        for (int i = 0; i < 16; ++i) { acc[i] = make_float2(0.f, 0.f); ws[i] = 0.f; }
#pragma unroll
        for (int i2 = 0; i2 < 23; ++i2) {
            int t = s0 - 8 + i2;                       // >= 8 always
            size_t off = (rbase + t) * D_ + d;
            ushort2 n2 = *(const ushort2*)(normh + off);
            ushort2 v2 = *(const ushort2*)(inflh + off);
            float m = magw[rbase + t];
            float2 vm = make_float2(m * (0.6f * fb(n2.x) + 0.4f * fb(v2.x)),
                                    m * (0.6f * fb(n2.y) + 0.4f * fb(v2.y)));
#pragma unroll
            for (int j = 0; j < 8; ++j) {              // tap j: contributes to s = t+8-j
                int idx = i2 - j;
                if (idx >= 0 && idx < 16) {            // compile-time after unroll
                    float lin = 0.1f + C * (float)j;
                    acc[idx].x += lin * vm.x;
                    acc[idx].y += lin * vm.y;
                    ws[idx] += lin * m;
                }
            }
        }
#pragma unroll
        for (int i = 0; i < 16; ++i) {
            float r = 1.0f / fmaxf(ws[i], 1e-8f);
            *(float2*)&out[((size_t)b * S_ + s0 + i) * D_ + d] =
                make_float2(acc[i].x * r, acc[i].y * r);
        }
    } else {
        // chunk 0: s = 0..15, variable w = min(s,8)
        for (int i = 0; i < 16; ++i) {
            int s = i;
            int w = (s < 8) ? s : 8;
            float rw = (w > 1) ? 0.9f / (float)(w - 1) : 0.0f;
            float2 acc = make_float2(0.f, 0.f); float wsum = 0.f;
            for (int j = 0; j < w; ++j) {
                int t = s - w + j;
                float m = magw[rbase + t];
                float wt = (0.1f + rw * (float)j) * m;
                size_t off = (rbase + t) * D_ + d;
                ushort2 n2 = *(const ushort2*)(normh + off);
                ushort2 v2 = *(const ushort2*)(inflh + off);
                acc.x += wt * (0.6f * fb(n2.x) + 0.4f * fb(v2.x));
                acc.y += wt * (0.6f * fb(n2.y) + 0.4f * fb(v2.y));
                wsum += wt;
            }
            float r = 1.0f / fmaxf(wsum, 1e-8f);
            *(float2*)&out[((size_t)b * S_ + s) * D_ + d] =
                make_float2(acc.x * r, acc.y * r);
        }
    }
}

// ---------------------------------------------------------------------------
extern "C" void kernel_launch(void* const* d_in, const int* in_sizes, int n_in,
                              void* d_out, int out_size, void* d_ws, size_t ws_size,
                              hipStream_t stream) {
    const float* emb  = (const float*)d_in[0];
    const float* guid = (const float*)d_in[1];
    float* out = (float*)d_out;
    char* ws = (char*)d_ws;

    float*  rg2   = (float*)(ws + WSOFF_RG2);
    float*  magw  = (float*)(ws + WSOFF_MAGW);
    short8* Bp1   = (short8*)(ws + WSOFF_BP1);
    short8* Bp2   = (short8*)(ws + WSOFF_BP2);
    short*  normh = (short*)(ws + WSOFF_NH);
    short*  inflh = (short*)(ws + WSOFF_IH);

    prep_kernel<<<384, 256, 0, stream>>>(guid, rg2, Bp1, Bp2);
    fused_kernel<<<RPAD / MT, 1024, 0, stream>>>(emb, Bp1, Bp2, rg2, magw, normh, inflh);
    combine_kernel<<<B_ * 128 * 2, 256, 0, stream>>>(magw, (const unsigned short*)normh,
                                                     (const unsigned short*)inflh, out);
}